// Round 14
// baseline (206.223 us; speedup 1.0000x reference)
//
#include <hip/hip_runtime.h>
#include <hip/hip_bf16.h>
#include <stdint.h>

#define B_ 8
#define S_ 2048
#define D_ 768
#define H_ 64
#define M_ (B_*S_)   // 16384 rows

typedef __attribute__((ext_vector_type(8))) short bf16x8;   // 8 bf16 = 4 VGPR (MFMA A/B frag)
typedef __attribute__((ext_vector_type(4))) float f32x4;    // MFMA C/D frag
typedef __attribute__((ext_vector_type(4))) float floatv4;
typedef __attribute__((ext_vector_type(4))) unsigned short u16x4;

__device__ __forceinline__ uint16_t f2bf(float f) {
    union { float f; uint32_t u; } c; c.f = f;
    return (uint16_t)((c.u + 0x7FFFu + ((c.u >> 16) & 1u)) >> 16);  // RNE
}

// ------------------------------------------- transpose + convert W (tiny)
// Wt[mat][h][d] = bf16(W[d][h] * scale); Wq gets 1/sqrt(64) * log2(e) folded.
__global__ __launch_bounds__(256) void k_convert_w(const float* __restrict__ Wk,
                                                   const float* __restrict__ Wq,
                                                   const float* __restrict__ Wv,
                                                   uint16_t* __restrict__ wt) {
    const int mat = blockIdx.y;
    const float* W = mat == 0 ? Wk : (mat == 1 ? Wq : Wv);
    const float scale = (mat == 1) ? 0.18033688011f : 1.0f;  // 0.125 * log2(e)
    uint16_t* out = wt + (size_t)mat * (H_ * D_);
    int i = blockIdx.x * 256 + threadIdx.x;      // coalesced read index
    int d = i >> 6, h = i & 63;
    out[h * D_ + d] = f2bf(W[i] * scale);
}

// ------------------------------- streaming QKV projection (no LDS staging)
// Evidence (r12): barrier-structured proj stuck at ~45us across ALL variants.
// This version has ZERO barriers in the main loop: A-frags load fp32 x
// DIRECTLY from global (16B/lane, MFMA layout: row=l15, k=g*8..+8), convert
// in-register; B-frags read L2-hot wt bf16 directly. Block = 16 rows x 64
// cols x 3 mats, 2 waves k-split (wave w: k in [384w, 384w+384)), one LDS
// merge at the end. Grid 1024 = 4 blocks/CU = 8 waves/CU; ~14 independent
// loads/kt in flight per wave (MLP) + TLP hide latency.
__global__ __launch_bounds__(128) void k_proj(const float* __restrict__ x,
                                              const uint16_t* __restrict__ wt,
                                              uint16_t* __restrict__ kb,
                                              uint16_t* __restrict__ qb,
                                              uint16_t* __restrict__ vt) {
    __shared__ float mbuf[12 * 4 * 64];         // 12KB merge buffer
    const int tid  = threadIdx.x;
    const int lane = tid & 63, wave = tid >> 6;  // 2 waves
    const int l15  = lane & 15, g = lane >> 4;
    const int m0   = blockIdx.x * 16;

    f32x4 acc[3][4] = {};                        // [mat][colgroup]

    const float* xbase = x + (size_t)(m0 + l15) * D_ + g * 8 + wave * 384;

#pragma unroll 2
    for (int kt = 0; kt < 12; ++kt) {
        // A-frag: rows m0+l15, k = wave*384 + kt*32 + g*8 .. +8 (fp32->bf16)
        floatv4 a0 = *(const floatv4*)(xbase + kt * 32);
        floatv4 a1 = *(const floatv4*)(xbase + kt * 32 + 4);
        bf16x8 a;
        a[0]=(short)f2bf(a0[0]); a[1]=(short)f2bf(a0[1]);
        a[2]=(short)f2bf(a0[2]); a[3]=(short)f2bf(a0[3]);
        a[4]=(short)f2bf(a1[0]); a[5]=(short)f2bf(a1[1]);
        a[6]=(short)f2bf(a1[2]); a[7]=(short)f2bf(a1[3]);
        const int k0 = wave * 384 + kt * 32 + g * 8;
#pragma unroll
        for (int mat = 0; mat < 3; ++mat)
#pragma unroll
            for (int cg = 0; cg < 4; ++cg) {
                // B-frag: cols cg*16+l15 (wt rows, L2-hot), same k slice
                bf16x8 b = *(const bf16x8*)(wt + (size_t)mat * (H_ * D_) +
                                            (size_t)(cg*16 + l15) * D_ + k0);
                acc[mat][cg] = __builtin_amdgcn_mfma_f32_16x16x32_bf16(
                                   a, b, acc[mat][cg], 0, 0, 0);
            }
    }

    // ---- k-split merge: wave 1 publishes, wave 0 adds + stores ----
    if (wave == 1) {
#pragma unroll
        for (int mat = 0; mat < 3; ++mat)
#pragma unroll
            for (int cg = 0; cg < 4; ++cg)
#pragma unroll
                for (int r = 0; r < 4; ++r)
                    mbuf[((mat*4 + cg)*4 + r)*64 + lane] = acc[mat][cg][r];
    }
    __syncthreads();
    if (wave == 0) {
        // epilogue: C layout col = l15 (+cg*16), row = g*4 + r (+m0)
#pragma unroll
        for (int mat = 0; mat < 3; ++mat)
#pragma unroll
            for (int cg = 0; cg < 4; ++cg) {
                int col  = cg*16 + l15;
                int row0 = m0 + g * 4;
                if (mat < 2) {
                    uint16_t* out = (mat == 0) ? kb : qb;
#pragma unroll
                    for (int r = 0; r < 4; ++r) {
                        float v = acc[mat][cg][r] + mbuf[((mat*4 + cg)*4 + r)*64 + lane];
                        out[(size_t)(row0 + r) * H_ + col] = f2bf(v);
                    }
                } else {
                    int bb = row0 >> 11, s = row0 & 2047;
                    u16x4 pk;
#pragma unroll
                    for (int r = 0; r < 4; ++r)
                        pk[r] = f2bf(acc[mat][cg][r] + mbuf[((mat*4 + cg)*4 + r)*64 + lane]);
                    *(u16x4*)(vt + ((size_t)bb * H_ + col) * S_ + s) = pk;
                }
            }
    }
}

// ------------------------------------------------------------ attention
// Evidence (r2/r5/r12): T x occupancy ~= const -> pure latency-bound; FETCH
// 17.6MB vs 6MB unique => XCD-scattered blocks re-fetch K/V from HBM (~900cy
// misses). Fixes: (1) kt-split x8: 8 waves/block x 4 kt each, VGPR<=128
// (launch_bounds(512,4)) -> 16 waves/CU, half the chain per wave;
// (2) XCD-aware 1-D grid: batch = bid&7 pins each batch's 768KB Q/K/V to one
// XCD's L2 (misses ~300cy, FETCH -> ~8MB). Inner kt body identical to r5
// (proven correct). Static-max softmax (C=4, exact shift-invariance).
// LDS 65KB: plds 8x4KB (reused as f32 o-merge) + o_buf4 32KB + l_buf 1KB.
__global__ __launch_bounds__(512, 4) void k_attn(const uint16_t* __restrict__ qb,
                                                 const uint16_t* __restrict__ kb,
                                                 const uint16_t* __restrict__ vt,
                                                 float* __restrict__ out) {
    __shared__ char smem[66560];
    const int tid  = threadIdx.x;
    const int lane = tid & 63, wave = tid >> 6;   // 8 waves
    const int l15 = lane & 15, g = lane >> 4;
    const int bid = blockIdx.x;
    const int batch = bid & 7;                    // XCD-pinned batch
    const int q0 = (bid >> 3) * 32;
    const size_t qrow = (size_t)batch * S_ + q0;
    const float MBIAS = 4.0f;                     // static log2-domain bound

    float* o_buf4 = (float*)(smem + 32768);       // [4][32][64]
    float* l_buf  = (float*)(smem + 65536);       // [8][32]

    // Q A-frags (rows qm*16+l15, k-dim = h)
    bf16x8 aq[2][2];
#pragma unroll
    for (int qm = 0; qm < 2; ++qm)
#pragma unroll
        for (int kk = 0; kk < 2; ++kk)
            aq[qm][kk] = *(const bf16x8*)(qb + (qrow + qm*16 + l15) * H_ + kk*32 + g*8);

    f32x4 o[2][4] = {};
    float Ls[2][4] = {};

    const uint16_t* kbase = kb + (size_t)batch * S_ * H_;
    const uint16_t* vbase = vt + (size_t)batch * H_ * S_;
    char* pl = smem + wave * 4096;
    const int kt0 = wave * 4;                     // 4 kt per wave

    // K prologue load (kt0)
    bf16x8 bk[4][2], bkn[4][2];
#pragma unroll
    for (int n = 0; n < 4; ++n)
#pragma unroll
        for (int kk = 0; kk < 2; ++kk)
            bk[n][kk] = *(const bf16x8*)(kbase + (size_t)(kt0*64 + n*16 + l15) * H_ + kk*32 + g*8);

#pragma unroll
    for (int j = 0; j < 4; ++j) {
        const int kt = kt0 + j;
        // prefetch K for kt+1
        if (j < 3) {
#pragma unroll
            for (int n = 0; n < 4; ++n)
#pragma unroll
                for (int kk = 0; kk < 2; ++kk)
                    bkn[n][kk] = *(const bf16x8*)(kbase + (size_t)((kt+1)*64 + n*16 + l15) * H_ + kk*32 + g*8);
        }
        // S = Q K^T
        f32x4 s[2][4] = {};
#pragma unroll
        for (int qm = 0; qm < 2; ++qm)
#pragma unroll
            for (int n = 0; n < 4; ++n)
#pragma unroll
                for (int kk = 0; kk < 2; ++kk)
                    s[qm][n] = __builtin_amdgcn_mfma_f32_16x16x32_bf16(
                                   aq[qm][kk], bk[n][kk], s[qm][n], 0, 0, 0);

        // V loads issued early
        bf16x8 bv[4][2];
#pragma unroll
        for (int nh = 0; nh < 4; ++nh)
#pragma unroll
            for (int kk = 0; kk < 2; ++kk)
                bv[nh][kk] = *(const bf16x8*)(vbase + (size_t)(nh*16 + l15) * S_ + kt*64 + kk*32 + g*8);

        // static-max softmax
#pragma unroll
        for (int qm = 0; qm < 2; ++qm)
#pragma unroll
            for (int r = 0; r < 4; ++r) {
                int row = qm*16 + g*4 + r;
#pragma unroll
                for (int n = 0; n < 4; ++n) {
                    float p = exp2f(s[qm][n][r] - MBIAS);
                    Ls[qm][r] += p;
                    int cb  = ((n*16 + l15) * 2) ^ ((row & 7) << 4);
                    *(uint16_t*)(pl + row*128 + cb) = f2bf(p);
                }
            }

        // PV
        bf16x8 pa[2][2];
#pragma unroll
        for (int qm = 0; qm < 2; ++qm)
#pragma unroll
            for (int kk = 0; kk < 2; ++kk) {
                int row = qm*16 + l15;
                int cb  = (kk*64 + g*16) ^ ((row & 7) << 4);
                pa[qm][kk] = *(const bf16x8*)(pl + row*128 + cb);
            }
#pragma unroll
        for (int qm = 0; qm < 2; ++qm)
#pragma unroll
            for (int nh = 0; nh < 4; ++nh)
#pragma unroll
                for (int kk = 0; kk < 2; ++kk)
                    o[qm][nh] = __builtin_amdgcn_mfma_f32_16x16x32_bf16(
                                    pa[qm][kk], bv[nh][kk], o[qm][nh], 0, 0, 0);
        if (j < 3) {
#pragma unroll
            for (int n = 0; n < 4; ++n)
#pragma unroll
                for (int kk = 0; kk < 2; ++kk)
                    bk[n][kk] = bkn[n][kk];
        }
    }

    // ---- merge: L partials ----
#pragma unroll
    for (int qm = 0; qm < 2; ++qm)
#pragma unroll
        for (int r = 0; r < 4; ++r) {
            float l = Ls[qm][r];
#pragma unroll
            for (int off = 1; off < 16; off <<= 1) l += __shfl_xor(l, off);
            if (l15 == 0) l_buf[wave*32 + qm*16 + g*4 + r] = l;
        }

    // ---- stage A: waves 4-7 publish o to o_buf4 ----
    if (wave >= 4) {
        float* dst = o_buf4 + (size_t)(wave - 4) * 32 * 64;
#pragma unroll
        for (int qm = 0; qm < 2; ++qm)
#pragma unroll
            for (int nh = 0; nh < 4; ++nh)
#pragma unroll
                for (int r = 0; r < 4; ++r)
                    dst[(qm*16 + nh*4 + r)*64 + lane] = o[qm][nh][r];
    }
    __syncthreads();                              // also fences all P reads

    // ---- stage B: waves 0-3 add partner, publish pair-sum into plds(f32) ----
    if (wave < 4) {
        float* src = o_buf4 + (size_t)wave * 32 * 64;
        float* dst = (float*)(smem + (size_t)wave * 8192);   // [32][64]
#pragma unroll
        for (int qm = 0; qm < 2; ++qm)
#pragma unroll
            for (int nh = 0; nh < 4; ++nh)
#pragma unroll
                for (int r = 0; r < 4; ++r) {
                    int i = qm*16 + nh*4 + r;
                    dst[i*64 + lane] = o[qm][nh][r] + src[i*64 + lane];
                }
    }
    __syncthreads();

    // ---- final: each wave reduces 4 of the 32 combos, scales, stores ----
    float* obase = out + qrow * H_;
#pragma unroll
    for (int ii = 0; ii < 4; ++ii) {
        int i = wave*4 + ii;
        int qm = i >> 4, nh = (i >> 2) & 3, r = i & 3;
        float tot = 0.f;
#pragma unroll
        for (int sl = 0; sl < 4; ++sl)
            tot += ((float*)(smem + (size_t)sl * 8192))[i*64 + lane];
        int row = qm*16 + g*4 + r, col = nh*16 + l15;
        float L = 0.f;
#pragma unroll
        for (int wv = 0; wv < 8; ++wv) L += l_buf[wv*32 + row];
        obase[(size_t)row * H_ + col] = tot / L;
    }
}

// ---------------------------------------------------------------- launch
extern "C" void kernel_launch(void* const* d_in, const int* in_sizes, int n_in,
                              void* d_out, int out_size, void* d_ws, size_t ws_size,
                              hipStream_t stream) {
    const float* x  = (const float*)d_in[0];
    const float* Wk = (const float*)d_in[1];
    const float* Wq = (const float*)d_in[2];
    const float* Wv = (const float*)d_in[3];
    float* out = (float*)d_out;

    uint16_t* ws = (uint16_t*)d_ws;
    uint16_t* wt = ws;                               // 3*H*D bf16 (0.3 MB)
    uint16_t* kb = wt + (size_t)3 * H_ * D_;         // M*H bf16   (2.1 MB)
    uint16_t* qb = kb + (size_t)M_ * H_;             // M*H bf16
    uint16_t* vt = qb + (size_t)M_ * H_;             // B*H*S bf16 (transposed V)

    k_convert_w<<<dim3(192, 3), dim3(256), 0, stream>>>(Wk, Wq, Wv, wt);
    k_proj<<<dim3(M_ / 16), dim3(128), 0, stream>>>(x, wt, kb, qb, vt);
    k_attn<<<dim3(512), dim3(512), 0, stream>>>(qb, kb, vt, out);
}